// Round 1
// baseline (176.719 us; speedup 1.0000x reference)
//
#include <hip/hip_runtime.h>

#define HIMG 256
#define WIMG 256
#define CCH  32
#define JBOX 64
#define BIMG 8
#define HGT  8

// One block per (b, j, h). Threads index the output column i (0..max_w-1).
// Box params + y-weights are block-uniform; x-weights per thread, reused
// across the 32-channel inner loop. Stores coalesced along i.
__global__ __launch_bounds__(256) void roi_kernel(
    const float* __restrict__ img,     // (B, C, HIMG, WIMG)
    const float* __restrict__ boxes,   // (B, J, 5)
    float* __restrict__ res,           // (B, J, C, HGT, max_w)
    float* __restrict__ mask,          // (B, J, max_w)
    int max_w)
{
    const int blk = blockIdx.x;       // bj*8 + h
    const int h   = blk & 7;
    const int bj  = blk >> 3;         // 0..511
    const int b   = bj >> 6;          // J = 64
    const int i   = threadIdx.x;

    // Per-box parameters (uniform across the block; scalar-cached loads).
    const float left = boxes[bj * 5 + 0];
    const float top  = boxes[bj * 5 + 1];
    const float bw   = boxes[bj * 5 + 2] - left;
    const float bh   = boxes[bj * 5 + 3] - top;

    // width = int32(bw/bh * 8) with f32 ops + truncation (matches numpy).
    const int   width  = (int)(bw / bh * 8.0f);
    const float each_w = bw / ((float)width - 1.0f);
    const float each_h = bh / 7.0f;

    if (i >= max_w) return;
    const bool in_w = (i < width);

    if (h == 0) {
        mask[(size_t)bj * max_w + i] = in_w ? 1.0f : 0.0f;
    }

    // x = i*each_w + left, y = h*each_h + top — force separate mul/add
    // roundings so floor() matches numpy bit-exactly.
    const float x = __fadd_rn(__fmul_rn((float)i, each_w), left);
    const float y = __fadd_rn(__fmul_rn((float)h, each_h), top);

    const int xf = (int)floorf(x);
    const int yf = (int)floorf(y);
    const int x0 = min(max(xf,     0), WIMG - 1);
    const int x1 = min(max(xf + 1, 0), WIMG - 1);
    const int y0 = min(max(yf,     0), HIMG - 1);
    const int y1 = min(max(yf + 1, 0), HIMG - 1);

    const float wx1 = (float)x1 - x;   // (x1f - x)
    const float wx0 = x - (float)x0;   // (x - x0f)
    const float wy1 = (float)y1 - y;
    const float wy0 = y - (float)y0;

    const float wa = wx1 * wy1;
    const float wb = wx1 * wy0;
    const float wc = wx0 * wy1;
    const float wd = wx0 * wy0;

    const size_t img_base = (size_t)b * CCH * HIMG * WIMG;
    const int o00 = y0 * WIMG + x0;
    const int o10 = y1 * WIMG + x0;
    const int o01 = y0 * WIMG + x1;
    const int o11 = y1 * WIMG + x1;

    // res[((bj*C + c)*HGT + h)*max_w + i]
    float* resp = res + ((size_t)bj * CCH * HGT + h) * (size_t)max_w + i;
    const size_t c_stride = (size_t)HGT * max_w;

    #pragma unroll 4
    for (int c = 0; c < CCH; ++c) {
        const float* im = img + img_base + (size_t)c * (HIMG * WIMG);
        const float va = im[o00];
        const float vb = im[o10];
        const float vc = im[o01];
        const float vd = im[o11];
        const float val = va * wa + vb * wb + vc * wc + vd * wd;
        resp[(size_t)c * c_stride] = in_w ? val : 0.0f;
    }
}

extern "C" void kernel_launch(void* const* d_in, const int* in_sizes, int n_in,
                              void* d_out, int out_size, void* d_ws, size_t ws_size,
                              hipStream_t stream) {
    const float* img   = (const float*)d_in[0];
    const float* boxes = (const float*)d_in[1];
    float* out = (float*)d_out;

    // out_size = max_w * (B*J*C*HGT + B*J) = max_w * 131584
    const int per_w = BIMG * JBOX * CCH * HGT + BIMG * JBOX;  // 131584
    const int max_w = out_size / per_w;

    float* res  = out;
    float* mask = out + (size_t)BIMG * JBOX * CCH * HGT * max_w;

    const int blocks = BIMG * JBOX * HGT;  // 4096
    roi_kernel<<<blocks, 256, 0, stream>>>(img, boxes, res, mask, max_w);
}